// Round 2
// baseline (180.309 us; speedup 1.0000x reference)
//
#include <hip/hip_runtime.h>
#include <cmath>

#define PHI_F   1.6180339887498949f
#define INV2PI  0.15915494309189535f
#define SQRT2F  1.41421356237309505f
#define TLASTF  (63.0f * 1.6180339887498949f)

typedef __attribute__((ext_vector_type(8))) short bf16x8;
typedef __attribute__((ext_vector_type(4))) float f32x4;

// ---------------------------------------------------------------------------
// Phase 1: rotation recurrence, scalar carry u = h_real + h_imag.
//   phi = u/lam + 2*(be + t*PHI);  u' = cos(phi)+sin(phi) = sqrt2*sin(phi+pi/4)
// carried as v = u/sqrt2:  v' = sin(2*pi*fract(fma(v, a2, b2)))
// 256 blocks x 256 threads: (b = blk>>1, d = (blk&1)*256 + tid)
// ---------------------------------------------------------------------------
__global__ __launch_bounds__(256) void rin_recurrence(
    const int* __restrict__ ids,      // (128, 64)
    const float* __restrict__ te,     // (1024, 1024): [0:512]=w, [512:1024]=b
    float* __restrict__ h)            // out: (128, 512)
{
    const int b = blockIdx.x >> 1;
    const int d = ((blockIdx.x & 1) << 8) + threadIdx.x;
    __shared__ int sid[64];
    if (threadIdx.x < 64) sid[threadIdx.x] = ids[b * 64 + threadIdx.x];
    __syncthreads();

    float v = 0.f;
    const int id0 = sid[0];
    float w  = te[id0 * 1024 + d];
    float be = te[id0 * 1024 + 512 + d];
    #pragma unroll 1
    for (int t = 0; t < 64; ++t) {
        const float rlam = __builtin_amdgcn_rcpf(1.0f + fabsf(w));   // off critical chain
        const float a2 = (SQRT2F * INV2PI) * rlam;
        const float b2 = fmaf(2.0f * INV2PI, be,
                              fmaf((float)t, 2.0f * PHI_F * INV2PI, 0.125f));
        if (t < 63) {  // prefetch next step's embedding row
            const int idn = sid[t + 1];
            w  = te[idn * 1024 + d];
            be = te[idn * 1024 + 512 + d];
        }
        v = __builtin_amdgcn_sinf(__builtin_amdgcn_fractf(fmaf(v, a2, b2)));
    }
    h[b * 512 + d] = SQRT2F * v;
}

// ---------------------------------------------------------------------------
// fp32 -> (hi, lo) bf16 split, 8 elements (RN-even via bit trick)
// ---------------------------------------------------------------------------
__device__ inline void split8(float4 u0, float4 u1, bf16x8& hi, bf16x8& lo) {
    float xs[8] = {u0.x, u0.y, u0.z, u0.w, u1.x, u1.y, u1.z, u1.w};
    #pragma unroll
    for (int i = 0; i < 8; ++i) {
        const unsigned u = __float_as_uint(xs[i]);
        const unsigned r = (u + 0x7fffu + ((u >> 16) & 1u)) & 0xffff0000u;
        hi[i] = (short)(r >> 16);
        const float l = xs[i] - __uint_as_float(r);
        const unsigned ul = __float_as_uint(l);
        lo[i] = (short)((ul + 0x7fffu + ((ul >> 16) & 1u)) >> 16);
    }
}

// ---------------------------------------------------------------------------
// One 16x16 NT fragment over full K: C[m][n] = sum_k A[m][k]*B[n][k]
// 2-term bf16 split -> 3 MFMAs per 32-wide k-step (fp32-level accuracy).
// A-frag: lane reads A[m0 + (l&15)][k + 8*(l>>4) .. +7] (contiguous 32B)
// B-frag: lane reads B[n0 + (l&15)][same k range]
// C/D: col = l&15, row = 4*(l>>4) + reg   [m89-verified]
// ---------------------------------------------------------------------------
template<int K>
__device__ inline f32x4 frag_nt(const float* __restrict__ A, const float* __restrict__ B,
                                int lda, int ldb, int m0, int n0, int lane, f32x4 acc)
{
    const int r  = lane & 15;
    const int ko = (lane >> 4) * 8;
    const float* ap = A + (size_t)(m0 + r) * lda + ko;
    const float* bp = B + (size_t)(n0 + r) * ldb + ko;
    #pragma unroll 2
    for (int kk = 0; kk < K; kk += 32) {
        const float4 a0 = *(const float4*)(ap + kk);
        const float4 a1 = *(const float4*)(ap + kk + 4);
        const float4 b0 = *(const float4*)(bp + kk);
        const float4 b1 = *(const float4*)(bp + kk + 4);
        bf16x8 ah, al, bh, bl;
        split8(a0, a1, ah, al);
        split8(b0, b1, bh, bl);
        acc = __builtin_amdgcn_mfma_f32_16x16x32_bf16(ah, bh, acc, 0, 0, 0);
        acc = __builtin_amdgcn_mfma_f32_16x16x32_bf16(ah, bl, acc, 0, 0, 0);
        acc = __builtin_amdgcn_mfma_f32_16x16x32_bf16(al, bh, acc, 0, 0, 0);
    }
    return acc;
}

// ---------------------------------------------------------------------------
// theta = h @ W^T + bias + t_last; ct = cos(theta), st = sin(theta)
// M=128, N=1024, K=512 -> 512 waves (one frag each) = 128 blocks
// ---------------------------------------------------------------------------
__global__ __launch_bounds__(256) void theta_gemm(
    const float* __restrict__ h, const float* __restrict__ W,
    const float* __restrict__ bias, float* __restrict__ ct, float* __restrict__ st)
{
    const int lane = threadIdx.x & 63;
    const int wid  = (blockIdx.x * 256 + threadIdx.x) >> 6;   // 0..511
    const int mt = wid >> 6, nt = wid & 63;
    f32x4 acc = {0.f, 0.f, 0.f, 0.f};
    acc = frag_nt<512>(h, W, 512, 512, mt * 16, nt * 16, lane, acc);

    const int col = lane & 15, rb = (lane >> 4) * 4;
    const int n = nt * 16 + col;
    const float bn = bias[n] + TLASTF;
    #pragma unroll
    for (int r = 0; r < 4; ++r) {
        const int m = mt * 16 + rb + r;
        const float fr = __builtin_amdgcn_fractf((acc[r] + bn) * INV2PI);
        ct[m * 1024 + n] = __builtin_amdgcn_cosf(fr);
        st[m * 1024 + n] = __builtin_amdgcn_sinf(fr);
    }
}

// ---------------------------------------------------------------------------
// h += silu(ct @ Pr^T + st @ Pi^T)
// M=128, N=512, K=1024 per pair -> 256 waves = 64 blocks
// ---------------------------------------------------------------------------
__global__ __launch_bounds__(256) void pv_gemm(
    const float* __restrict__ ct, const float* __restrict__ st,
    const float* __restrict__ Pr, const float* __restrict__ Pi,
    float* __restrict__ h)
{
    const int lane = threadIdx.x & 63;
    const int wid  = (blockIdx.x * 256 + threadIdx.x) >> 6;   // 0..255
    const int mt = wid >> 5, nt = wid & 31;
    f32x4 acc = {0.f, 0.f, 0.f, 0.f};
    acc = frag_nt<1024>(ct, Pr, 1024, 1024, mt * 16, nt * 16, lane, acc);
    acc = frag_nt<1024>(st, Pi, 1024, 1024, mt * 16, nt * 16, lane, acc);

    const int col = lane & 15, rb = (lane >> 4) * 4;
    const int dn = nt * 16 + col;
    #pragma unroll
    for (int r = 0; r < 4; ++r) {
        const int m = mt * 16 + rb + r;
        const float s = acc[r];
        const float sig = __builtin_amdgcn_rcpf(
            1.0f + __builtin_amdgcn_exp2f(-1.4426950408889634f * s));
        h[m * 512 + dn] += s * sig;
    }
}

// ---------------------------------------------------------------------------
// logits = h @ oproj^T   (M=128, N=1024, K=512) -> 512 waves = 128 blocks
// ---------------------------------------------------------------------------
__global__ __launch_bounds__(256) void logits_gemm(
    const float* __restrict__ h, const float* __restrict__ oproj,
    float* __restrict__ out)
{
    const int lane = threadIdx.x & 63;
    const int wid  = (blockIdx.x * 256 + threadIdx.x) >> 6;   // 0..511
    const int mt = wid >> 6, nt = wid & 63;
    f32x4 acc = {0.f, 0.f, 0.f, 0.f};
    acc = frag_nt<512>(h, oproj, 512, 512, mt * 16, nt * 16, lane, acc);

    const int col = lane & 15, rb = (lane >> 4) * 4;
    const int n = nt * 16 + col;
    #pragma unroll
    for (int r = 0; r < 4; ++r) {
        const int m = mt * 16 + rb + r;
        out[m * 1024 + n] = acc[r];
    }
}

// ---------------------------------------------------------------------------
// B=128, S=64, V=1024, D=512, N=1024, L=2
// inputs: 0 ids(128,64) i32 | 1 te(1024,1024) | 2 W(2,1024,512) | 3 bias(2,1024)
//         4 Pr(2,512,1024) | 5 Pi(2,512,1024) | 6 oproj(1024,512)
// out: (128,1024) f32;  ws: h 64K | ct 128K | st 128K floats (~1.3 MB)
// ---------------------------------------------------------------------------
extern "C" void kernel_launch(void* const* d_in, const int* in_sizes, int n_in,
                              void* d_out, int out_size, void* d_ws, size_t ws_size,
                              hipStream_t stream) {
    const int*   ids   = (const int*)d_in[0];
    const float* te    = (const float*)d_in[1];
    const float* W     = (const float*)d_in[2];
    const float* bias  = (const float*)d_in[3];
    const float* Pr    = (const float*)d_in[4];
    const float* Pi    = (const float*)d_in[5];
    const float* oproj = (const float*)d_in[6];
    float* out = (float*)d_out;

    float* ws = (float*)d_ws;
    float* h  = ws;             // 65536
    float* ct = h + 65536;      // 131072
    float* st = ct + 131072;    // 131072

    rin_recurrence<<<256, 256, 0, stream>>>(ids, te, h);

    for (int l = 0; l < 2; ++l) {
        theta_gemm<<<128, 256, 0, stream>>>(
            h, W + (size_t)l * 524288, bias + l * 1024, ct, st);
        pv_gemm<<<64, 256, 0, stream>>>(
            ct, st, Pr + (size_t)l * 524288, Pi + (size_t)l * 524288, h);
    }

    logits_gemm<<<128, 256, 0, stream>>>(h, oproj, out);
}

// Round 3
// 63.859 us; speedup vs baseline: 2.8235x; 2.8235x over previous
//
#include <hip/hip_runtime.h>
#include <cmath>

#define PHI_F   1.6180339887498949f
#define INV2PI  0.15915494309189535f
#define SQRT2F  1.41421356237309505f
#define TLASTF  (63.0f * 1.6180339887498949f)
#define LOG2EF  1.4426950408889634f

typedef __attribute__((ext_vector_type(8))) short bf16x8;
typedef __attribute__((ext_vector_type(4))) float f32x4;

// fp32 -> (hi, lo) bf16 (RN-even via bit trick)
__device__ inline void split1(float x, unsigned short& hi, unsigned short& lo) {
    const unsigned u = __float_as_uint(x);
    const unsigned r = (u + 0x7fffu + ((u >> 16) & 1u)) & 0xffff0000u;
    hi = (unsigned short)(r >> 16);
    const float l = x - __uint_as_float(r);
    const unsigned ul = __float_as_uint(l);
    lo = (unsigned short)((ul + 0x7fffu + ((ul >> 16) & 1u)) >> 16);
}

// ---------------------------------------------------------------------------
// prep: [blocks 0..255]   rotation recurrence -> h (fp32 + hi/lo bf16)
//       [blocks 256..3839] split all weights into hi/lo bf16 (flat layout)
// weight flat order (floats): W[0,1048576) Pr[1048576,2097152)
//                             Pi[2097152,3145728) op[3145728,3670016)
// ---------------------------------------------------------------------------
__global__ __launch_bounds__(256) void prep(
    const int* __restrict__ ids, const float* __restrict__ te,
    const float* __restrict__ W, const float* __restrict__ Pr,
    const float* __restrict__ Pi, const float* __restrict__ op,
    unsigned short* __restrict__ whi, unsigned short* __restrict__ wlo,
    float* __restrict__ h, unsigned short* __restrict__ hh,
    unsigned short* __restrict__ hl)
{
    if (blockIdx.x < 256) {
        const int bb = blockIdx.x;
        const int b = bb >> 1;
        const int d = ((bb & 1) << 8) + threadIdx.x;
        __shared__ int sid[64];
        if (threadIdx.x < 64) sid[threadIdx.x] = ids[b * 64 + threadIdx.x];
        __syncthreads();
        float v = 0.f;
        const int id0 = sid[0];
        float w  = te[id0 * 1024 + d];
        float be = te[id0 * 1024 + 512 + d];
        #pragma unroll 1
        for (int t = 0; t < 64; ++t) {
            const float rlam = __builtin_amdgcn_rcpf(1.0f + fabsf(w));
            const float a2 = (SQRT2F * INV2PI) * rlam;
            const float b2 = fmaf(2.0f * INV2PI, be,
                                  fmaf((float)t, 2.0f * PHI_F * INV2PI, 0.125f));
            if (t < 63) {
                const int idn = sid[t + 1];
                w  = te[idn * 1024 + d];
                be = te[idn * 1024 + 512 + d];
            }
            v = __builtin_amdgcn_sinf(__builtin_amdgcn_fractf(fmaf(v, a2, b2)));
        }
        const float u = SQRT2F * v;
        h[b * 512 + d] = u;
        unsigned short uh, ul;
        split1(u, uh, ul);
        hh[b * 512 + d] = uh;
        hl[b * 512 + d] = ul;
    } else {
        const int j = ((blockIdx.x - 256) * 256 + threadIdx.x) * 4;
        const float* src; int off;
        if (j < 1048576)      { src = W;  off = j; }
        else if (j < 2097152) { src = Pr; off = j - 1048576; }
        else if (j < 3145728) { src = Pi; off = j - 2097152; }
        else                  { src = op; off = j - 3145728; }
        const float4 v = *(const float4*)(src + off);
        ushort4 h4, l4;
        split1(v.x, h4.x, l4.x);
        split1(v.y, h4.y, l4.y);
        split1(v.z, h4.z, l4.z);
        split1(v.w, h4.w, l4.w);
        *(ushort4*)(whi + j) = h4;
        *(ushort4*)(wlo + j) = l4;
    }
}

// ---------------------------------------------------------------------------
// One 16x16 NT fragment over k-chunk [k0, k0+KC): pure loads + 3 MFMAs/step.
// A-frag: lane reads A[m0+(l&15)][k + 8*(l>>4) .. +7]; B same with n-row.
// C/D: col = l&15, row = 4*(l>>4) + reg   [empirically verified r1]
// ---------------------------------------------------------------------------
template<int KC>
__device__ inline f32x4 frag3(const unsigned short* __restrict__ Ah,
                              const unsigned short* __restrict__ Al,
                              const unsigned short* __restrict__ Bh,
                              const unsigned short* __restrict__ Bl,
                              int lda, int ldb, int m0, int n0, int k0,
                              int lane, f32x4 acc)
{
    const int rr = lane & 15;
    const int ko = (lane >> 4) * 8;
    const unsigned short* aph = Ah + (size_t)(m0 + rr) * lda + k0 + ko;
    const unsigned short* apl = Al + (size_t)(m0 + rr) * lda + k0 + ko;
    const unsigned short* bph = Bh + (size_t)(n0 + rr) * ldb + k0 + ko;
    const unsigned short* bpl = Bl + (size_t)(n0 + rr) * ldb + k0 + ko;
    f32x4 acc2 = {0.f, 0.f, 0.f, 0.f};
    #pragma unroll
    for (int kk = 0; kk < KC; kk += 32) {
        const bf16x8 ah = *(const bf16x8*)(aph + kk);
        const bf16x8 al = *(const bf16x8*)(apl + kk);
        const bf16x8 bh = *(const bf16x8*)(bph + kk);
        const bf16x8 bl = *(const bf16x8*)(bpl + kk);
        acc  = __builtin_amdgcn_mfma_f32_16x16x32_bf16(ah, bh, acc,  0, 0, 0);
        acc2 = __builtin_amdgcn_mfma_f32_16x16x32_bf16(ah, bl, acc2, 0, 0, 0);
        acc2 = __builtin_amdgcn_mfma_f32_16x16x32_bf16(al, bh, acc2, 0, 0, 0);
    }
    acc[0] += acc2[0]; acc[1] += acc2[1]; acc[2] += acc2[2]; acc[3] += acc2[3];
    return acc;
}

// ---------------------------------------------------------------------------
// theta = h @ W^T + bias + t_last; ct/st = cos/sin(theta) written as hi/lo bf16
// M=128, N=1024, K=512. 512 blocks (mt=bid>>6, nt=bid&63) x 4 waves (split-K 128)
// ---------------------------------------------------------------------------
__global__ __launch_bounds__(256) void theta_gemm(
    const unsigned short* __restrict__ hh, const unsigned short* __restrict__ hl,
    const unsigned short* __restrict__ Wh, const unsigned short* __restrict__ Wl,
    const float* __restrict__ bias,
    unsigned short* __restrict__ cth, unsigned short* __restrict__ ctl,
    unsigned short* __restrict__ sth, unsigned short* __restrict__ stl)
{
    __shared__ float red[4][260];
    const int lane = threadIdx.x & 63;
    const int w = threadIdx.x >> 6;
    const int nt = blockIdx.x & 63, mt = blockIdx.x >> 6;
    f32x4 acc = {0.f, 0.f, 0.f, 0.f};
    acc = frag3<128>(hh, hl, Wh, Wl, 512, 512, mt * 16, nt * 16, w * 128, lane, acc);
    *(float4*)&red[w][lane * 4] = (float4){acc[0], acc[1], acc[2], acc[3]};
    __syncthreads();
    if (w < 2) {
        float4 s = {0.f, 0.f, 0.f, 0.f};
        #pragma unroll
        for (int ww = 0; ww < 4; ++ww) {
            const float4 p = *(const float4*)&red[ww][lane * 4];
            s.x += p.x; s.y += p.y; s.z += p.z; s.w += p.w;
        }
        const int col = lane & 15, rb = (lane >> 4) * 4;
        const int n = nt * 16 + col;
        const float bn = bias[n] + TLASTF;
        const float sv[4] = {s.x, s.y, s.z, s.w};
        unsigned short* dh = (w == 0) ? cth : sth;
        unsigned short* dl = (w == 0) ? ctl : stl;
        #pragma unroll
        for (int r = 0; r < 4; ++r) {
            const int m = mt * 16 + rb + r;
            const float fr = __builtin_amdgcn_fractf((sv[r] + bn) * INV2PI);
            const float v = (w == 0) ? __builtin_amdgcn_cosf(fr)
                                     : __builtin_amdgcn_sinf(fr);
            unsigned short vh, vl;
            split1(v, vh, vl);
            dh[m * 1024 + n] = vh;
            dl[m * 1024 + n] = vl;
        }
    }
}

// ---------------------------------------------------------------------------
// h += silu(ct @ Pr^T + st @ Pi^T); h rewritten as fp32 + hi/lo bf16
// M=128, N=512, K=1024 per pair. 256 blocks (mt=bid>>5, nt=bid&31) x 8 waves
// wave w: pair = w>>2 (0: ct*Pr, 1: st*Pi), k-chunk = (w&3)*256
// ---------------------------------------------------------------------------
__global__ __launch_bounds__(512) void pv_gemm(
    const unsigned short* __restrict__ cth, const unsigned short* __restrict__ ctl,
    const unsigned short* __restrict__ sth, const unsigned short* __restrict__ stl,
    const unsigned short* __restrict__ Prh, const unsigned short* __restrict__ Prl,
    const unsigned short* __restrict__ Pih, const unsigned short* __restrict__ Pil,
    float* __restrict__ h, unsigned short* __restrict__ hh,
    unsigned short* __restrict__ hl)
{
    __shared__ float red[8][260];
    const int lane = threadIdx.x & 63;
    const int w = threadIdx.x >> 6;
    const int nt = blockIdx.x & 31, mt = blockIdx.x >> 5;
    const int p = w >> 2, k0 = (w & 3) * 256;
    const unsigned short* Ah = p ? sth : cth;
    const unsigned short* Al = p ? stl : ctl;
    const unsigned short* Bh = p ? Pih : Prh;
    const unsigned short* Bl = p ? Pil : Prl;
    f32x4 acc = {0.f, 0.f, 0.f, 0.f};
    acc = frag3<256>(Ah, Al, Bh, Bl, 1024, 1024, mt * 16, nt * 16, k0, lane, acc);
    *(float4*)&red[w][lane * 4] = (float4){acc[0], acc[1], acc[2], acc[3]};
    __syncthreads();
    if (w == 0) {
        float4 s = {0.f, 0.f, 0.f, 0.f};
        #pragma unroll
        for (int ww = 0; ww < 8; ++ww) {
            const float4 q = *(const float4*)&red[ww][lane * 4];
            s.x += q.x; s.y += q.y; s.z += q.z; s.w += q.w;
        }
        const int col = lane & 15, rb = (lane >> 4) * 4;
        const int dn = nt * 16 + col;
        const float sv[4] = {s.x, s.y, s.z, s.w};
        #pragma unroll
        for (int r = 0; r < 4; ++r) {
            const int m = mt * 16 + rb + r;
            const float x = sv[r];
            const float sig = __builtin_amdgcn_rcpf(
                1.0f + __builtin_amdgcn_exp2f(-LOG2EF * x));
            const float val = h[m * 512 + dn] + x * sig;
            h[m * 512 + dn] = val;
            unsigned short vh, vl;
            split1(val, vh, vl);
            hh[m * 512 + dn] = vh;
            hl[m * 512 + dn] = vl;
        }
    }
}

// ---------------------------------------------------------------------------
// logits = h @ oproj^T  (M=128, N=1024, K=512). 512 blocks x 4 waves
// ---------------------------------------------------------------------------
__global__ __launch_bounds__(256) void logits_gemm(
    const unsigned short* __restrict__ hh, const unsigned short* __restrict__ hl,
    const unsigned short* __restrict__ oph, const unsigned short* __restrict__ opl,
    float* __restrict__ out)
{
    __shared__ float red[4][260];
    const int lane = threadIdx.x & 63;
    const int w = threadIdx.x >> 6;
    const int nt = blockIdx.x & 63, mt = blockIdx.x >> 6;
    f32x4 acc = {0.f, 0.f, 0.f, 0.f};
    acc = frag3<128>(hh, hl, oph, opl, 512, 512, mt * 16, nt * 16, w * 128, lane, acc);
    *(float4*)&red[w][lane * 4] = (float4){acc[0], acc[1], acc[2], acc[3]};
    __syncthreads();
    if (w == 0) {
        float4 s = {0.f, 0.f, 0.f, 0.f};
        #pragma unroll
        for (int ww = 0; ww < 4; ++ww) {
            const float4 q = *(const float4*)&red[ww][lane * 4];
            s.x += q.x; s.y += q.y; s.z += q.z; s.w += q.w;
        }
        const int col = lane & 15, rb = (lane >> 4) * 4;
        const int n = nt * 16 + col;
        const float sv[4] = {s.x, s.y, s.z, s.w};
        #pragma unroll
        for (int r = 0; r < 4; ++r)
            out[(mt * 16 + rb + r) * 1024 + n] = sv[r];
    }
}

// ---------------------------------------------------------------------------
// B=128, S=64, V=1024, D=512, N=1024, L=2
// ws: whi/wlo 3,670,016 ushort each | h 65,536 f32 | hh/hl 65,536 ushort
//     cth/ctl/sth/stl 131,072 ushort each   (~15.5 MiB total)
// ---------------------------------------------------------------------------
extern "C" void kernel_launch(void* const* d_in, const int* in_sizes, int n_in,
                              void* d_out, int out_size, void* d_ws, size_t ws_size,
                              hipStream_t stream) {
    const int*   ids   = (const int*)d_in[0];
    const float* te    = (const float*)d_in[1];
    const float* W     = (const float*)d_in[2];
    const float* bias  = (const float*)d_in[3];
    const float* Pr    = (const float*)d_in[4];
    const float* Pi    = (const float*)d_in[5];
    const float* oproj = (const float*)d_in[6];
    float* out = (float*)d_out;

    unsigned short* whi = (unsigned short*)d_ws;     // 3,670,016
    unsigned short* wlo = whi + 3670016;             // 3,670,016
    float*          h   = (float*)(wlo + 3670016);   // 65,536 f32
    unsigned short* hh  = (unsigned short*)(h + 65536);
    unsigned short* hl  = hh + 65536;
    unsigned short* cth = hl + 65536;                // 131,072
    unsigned short* ctl = cth + 131072;
    unsigned short* sth = ctl + 131072;
    unsigned short* stl = sth + 131072;

    prep<<<3840, 256, 0, stream>>>(ids, te, W, Pr, Pi, oproj,
                                   whi, wlo, h, hh, hl);

    for (int l = 0; l < 2; ++l) {
        theta_gemm<<<512, 256, 0, stream>>>(
            hh, hl, whi + (size_t)l * 524288, wlo + (size_t)l * 524288,
            bias + l * 1024, cth, ctl, sth, stl);
        pv_gemm<<<256, 512, 0, stream>>>(
            cth, ctl, sth, stl,
            whi + 1048576 + (size_t)l * 524288, wlo + 1048576 + (size_t)l * 524288,
            whi + 2097152 + (size_t)l * 524288, wlo + 2097152 + (size_t)l * 524288,
            h, hh, hl);
    }

    logits_gemm<<<512, 256, 0, stream>>>(
        hh, hl, whi + 3145728, wlo + 3145728, out);
}